// Round 9
// baseline (208.912 us; speedup 1.0000x reference)
//
#include <hip/hip_runtime.h>

// 2-layer LSTM (B=4096, T=256, I=38, H1=50, H2=15) + FC on last step.
// R9: SB=16, 512 thr / 8 waves, grid=256 (1 block/CU). Single barrier/step,
// wave-private pre-act round-trip (s_pre[tile][col][20]). NO undefined
// values: all 4 A-fragments always loaded; slot1 always runs 4 MFMAs
// (out-of-range weights fetched as exact 0). Update = R7's verified mapping
// duplicated over seq halves (sequ, sequ+8). 2-step-ahead x prefetch.
// L2 pipelined one step behind L1.

typedef _Float16 f16x8 __attribute__((ext_vector_type(8)));
typedef float    f32x4 __attribute__((ext_vector_type(4)));

#if __has_builtin(__builtin_amdgcn_exp2f)
#define DEV_EXP2(x) __builtin_amdgcn_exp2f(x)
#else
#define DEV_EXP2(x) exp2f(x)
#endif
#if __has_builtin(__builtin_amdgcn_rcpf)
#define DEV_RCP(x) __builtin_amdgcn_rcpf(x)
#else
#define DEV_RCP(x) (1.0f/(x))
#endif

#define I1 38
#define H1 50
#define H2 15
#define NC 14
#define TT 256
#define SB 16
// A-row (f16): [x:0..37 | h1:38..87 | h2:88..102 | zero:..127 | pad..135]
#define XS 136
#define NTH 512
#define PSTR 20
#define L2E 2.885390081777927f
#define L1E 1.442695040888963f

#define MF(A,B,C) __builtin_amdgcn_mfma_f32_16x16x32_f16((A),(B),(C),0,0,0)

__device__ __forceinline__ float sigm(float v)  { return DEV_RCP(1.f + DEV_EXP2(-L1E * v)); }
__device__ __forceinline__ float tanh_f(float v){ return 1.f - 2.f * DEV_RCP(1.f + DEV_EXP2(L2E * v)); }

__device__ __forceinline__ void lstm_upd(const float* p, float& c, _Float16* dst) {
  float ig = sigm(p[0]),        fg = sigm(p[PSTR]);
  float gg = tanh_f(p[2*PSTR]), og = sigm(p[3*PSTR]);
  c = fg * c + ig * gg;
  *dst = (_Float16)(og * tanh_f(c));
}

__launch_bounds__(NTH, 2)
__global__ void lstm2_fused(const float* __restrict__ x,
                            const float* __restrict__ w_ih1, const float* __restrict__ w_hh1,
                            const float* __restrict__ b_ih1, const float* __restrict__ b_hh1,
                            const float* __restrict__ w_ih2, const float* __restrict__ w_hh2,
                            const float* __restrict__ b_ih2, const float* __restrict__ b_hh2,
                            const float* __restrict__ w_fc, const float* __restrict__ b_fc,
                            float* __restrict__ out)
{
  __shared__ __align__(16) _Float16 bufA[2][SB][XS];
  __shared__ __align__(16) float    s_pre[17][16][PSTR];   // [tile][col][seq]

  const int tid  = threadIdx.x;
  const int wv   = tid >> 6;          // 0..7
  const int lane = tid & 63;
  const int lm   = lane & 15;         // A seq row / B-C col
  const int lk   = lane >> 4;         // k chunk / C row group
  const int blk  = blockIdx.x;
  const float* xblk = x + (size_t)blk * SB * TT * I1;

  // ---- zero A buffers ----
  for (int i = tid; i < 2*SB*XS; i += NTH) ((_Float16*)bufA)[i] = (_Float16)0.f;

  // ---- weight element fetch (unified-k, gate-row r = 4u+g) ----
  auto welem = [&](bool il1, bool valid, int u, int g, int k) -> _Float16 {
    float w = 0.f;
    if (valid) {
      if (il1) {
        if (k < I1)                w = w_ih1[(g*H1 + u)*I1 + k];
        else if (k < I1 + H1)      w = w_hh1[(g*H1 + u)*H1 + (k - I1)];
      } else {
        if (k >= I1 && k < I1+H1)             w = w_ih2[(g*H2 + u)*H1 + (k - I1)];
        else if (k >= I1+H1 && k < I1+H1+H2)  w = w_hh2[(g*H2 + u)*H2 + (k - I1 - H1)];
      }
    }
    return (_Float16)w;
  };

  // ---- slot geometry: wave wv owns tiles {wv, wv+8}; wv0 also tile 16 ----
  const int t1 = wv + 8;
  const int r0 = wv*16 + lm, u0q = r0 >> 2, g0 = r0 & 3;     // always L1
  const int r1 = t1*16 + lm, q1 = r1 >> 2, g1 = r1 & 3;
  const bool il1s1 = (q1 < H1);
  const int  u1 = il1s1 ? q1 : (q1 - H1);
  const bool w16 = (wv == 0);
  const bool c16 = w16 && (lm < 4);         // tile16 valid cols: quad 64, g=lm

  const float sb0 = b_ih1[g0*H1 + u0q] + b_hh1[g0*H1 + u0q];
  const float sb1 = il1s1 ? (b_ih1[g1*H1 + u1] + b_hh1[g1*H1 + u1])
                          : (b_ih2[g1*H2 + u1] + b_hh2[g1*H2 + u1]);
  const float sb16 = c16 ? (b_ih2[lm*H2 + 14] + b_hh2[lm*H2 + 14]) : 0.f;

  f16x8 W0[3], W1[4], W16[3];
  #pragma unroll
  for (int ks = 0; ks < 3; ++ks) {
    f16x8 v;
    #pragma unroll
    for (int e = 0; e < 8; ++e) v[e] = welem(true, true, u0q, g0, ks*32 + lk*8 + e);
    W0[ks] = v;
  }
  #pragma unroll
  for (int ks = 0; ks < 4; ++ks) {
    f16x8 v;
    #pragma unroll
    for (int e = 0; e < 8; ++e) v[e] = welem(il1s1, true, u1, g1, ks*32 + lk*8 + e);
    W1[ks] = v;
  }
  #pragma unroll
  for (int j = 0; j < 3; ++j) {
    f16x8 v;
    #pragma unroll
    for (int e = 0; e < 8; ++e) v[e] = welem(false, c16, 14, lm & 3, (j+1)*32 + lk*8 + e);
    W16[j] = v;
  }

  // ---- update mapping (R7-verified, x2 seq halves): lane = sl*32+sequ*4+qlp ----
  const int sl   = lane >> 5;
  const int l5   = lane & 31;
  const int qlp  = l5 & 3;
  const int sequ = l5 >> 2;                  // 0..7
  const int tileU = sl ? t1 : wv;
  const int quadU = 4*tileU + qlp;           // 0..63
  const bool il1U = (quadU < H1);
  const int  uU   = il1U ? quadU : (quadU - H1);
  const int  dU   = il1U ? (38 + uU) : (88 + uU);
  const float* pLo = &s_pre[tileU][4*qlp][sequ];
  const float* pHi = &s_pre[tileU][4*qlp][sequ + 8];
  // tile16 pair (wv0 lanes 0..7): quad 64 = L2 u14
  const bool hasC = w16 && (lane < 8);
  const int  seqC = lane & 7;
  const float* pCl = &s_pre[16][0][seqC];
  const float* pCh = &s_pre[16][0][seqC + 8];

  // ---- x staging: 608 f32/step over 512 threads ----
  const int e1x = tid + 512;
  const bool v1 = (tid < SB*I1 - 512);       // tid < 96
  const int s0 = tid / I1,  k0 = tid % I1;
  const int s1 = e1x / I1,  k1 = e1x % I1;
  const int gb0 = s0*TT*I1 + k0, gb1 = v1 ? (s1*TT*I1 + k1) : 0;
  const int lb0 = s0*XS + k0,    lb1 = v1 ? (s1*XS + k1) : 0;

  __syncthreads();              // zeros visible
  {                             // stage x(0)
    _Float16* b0 = &bufA[0][0][0];
    b0[lb0] = (_Float16)xblk[gb0];
    if (v1) b0[lb1] = (_Float16)xblk[gb1];
  }
  float xA0 = 0.f, xA1 = 0.f, xB0 = 0.f, xB1 = 0.f;
  xA0 = xblk[gb0 + I1];                     // prefetch x(1)
  if (v1) xA1 = xblk[gb1 + I1];
  __syncthreads();

  float cLo = 0.f, cHi = 0.f, cCl = 0.f, cCh = 0.f;

#define STEP(T, XC0, XC1, XN0, XN1) do {                                        \
    _Float16* cur = &bufA[(T) & 1][0][0];                                       \
    _Float16* nxt = &bufA[((T) & 1) ^ 1][0][0];                                 \
    if ((T) + 2 < TT) {                                                         \
      const int go = ((T) + 2) * I1;                                            \
      XN0 = xblk[gb0 + go];                                                     \
      if (v1) XN1 = xblk[gb1 + go];                                             \
    }                                                                           \
    f16x8 a0 = *(const f16x8*)(cur + lm*XS +      lk*8);                        \
    f16x8 a1 = *(const f16x8*)(cur + lm*XS + 32 + lk*8);                        \
    f16x8 a2 = *(const f16x8*)(cur + lm*XS + 64 + lk*8);                        \
    f16x8 a3 = *(const f16x8*)(cur + lm*XS + 96 + lk*8);                        \
    {                                                                           \
      f32x4 acc = (f32x4){sb0, sb0, sb0, sb0};                                  \
      acc = MF(a0, W0[0], acc);                                                 \
      acc = MF(a1, W0[1], acc);                                                 \
      acc = MF(a2, W0[2], acc);                                                 \
      *(f32x4*)&s_pre[wv][lm][4*lk] = acc;                                      \
    }                                                                           \
    {                                                                           \
      f32x4 acc = (f32x4){sb1, sb1, sb1, sb1};                                  \
      acc = MF(a0, W1[0], acc);                                                 \
      acc = MF(a1, W1[1], acc);                                                 \
      acc = MF(a2, W1[2], acc);                                                 \
      acc = MF(a3, W1[3], acc);                                                 \
      *(f32x4*)&s_pre[t1][lm][4*lk] = acc;                                      \
    }                                                                           \
    if (w16) {                                                                  \
      f32x4 acc = (f32x4){sb16, sb16, sb16, sb16};                              \
      acc = MF(a1, W16[0], acc);                                                \
      acc = MF(a2, W16[1], acc);                                                \
      acc = MF(a3, W16[2], acc);                                                \
      *(f32x4*)&s_pre[16][lm][4*lk] = acc;                                      \
    }                                                                           \
    {                                                                           \
      const bool up = il1U ? ((T) < TT) : ((T) >= 1);                           \
      if (up) {                                                                 \
        lstm_upd(pLo, cLo, nxt + sequ*XS + dU);                                 \
        lstm_upd(pHi, cHi, nxt + (sequ + 8)*XS + dU);                           \
      }                                                                         \
    }                                                                           \
    if (hasC && (T) >= 1) {                                                     \
      lstm_upd(pCl, cCl, nxt + seqC*XS + 102);                                  \
      lstm_upd(pCh, cCh, nxt + (seqC + 8)*XS + 102);                            \
    }                                                                           \
    if ((T) + 1 < TT) {                                                         \
      nxt[lb0] = (_Float16)XC0;                                                 \
      if (v1) nxt[lb1] = (_Float16)XC1;                                         \
    }                                                                           \
    __syncthreads();                                                            \
  } while (0)

  int t = 0;
  for (;;) {
    STEP(t, xA0, xA1, xB0, xB1);
    if (++t > TT) break;
    STEP(t, xB0, xB1, xA0, xA1);
    if (++t > TT) break;
  }
#undef STEP

  // ---- FC on h2(255) (bufA[1], cols 88..102) ----
  if (tid < SB*NC) {
    int s = tid / NC, n = tid % NC;
    float acc = b_fc[n];
    #pragma unroll
    for (int u = 0; u < H2; ++u)
      acc += (float)bufA[1][s][88 + u] * w_fc[n*H2 + u];
    out[((size_t)blk*SB + s)*NC + n] = acc;
  }
}

extern "C" void kernel_launch(void* const* d_in, const int* in_sizes, int n_in,
                              void* d_out, int out_size, void* d_ws, size_t ws_size,
                              hipStream_t stream) {
  (void)n_in; (void)d_ws; (void)ws_size; (void)out_size;
  const float* x     = (const float*)d_in[0];
  const float* w_ih1 = (const float*)d_in[1];
  const float* w_hh1 = (const float*)d_in[2];
  const float* b_ih1 = (const float*)d_in[3];
  const float* b_hh1 = (const float*)d_in[4];
  const float* w_ih2 = (const float*)d_in[5];
  const float* w_hh2 = (const float*)d_in[6];
  const float* b_ih2 = (const float*)d_in[7];
  const float* b_hh2 = (const float*)d_in[8];
  const float* w_fc  = (const float*)d_in[9];
  const float* b_fc  = (const float*)d_in[10];
  float* out = (float*)d_out;

  const int B = in_sizes[0] / (TT * I1);   // 4096
  dim3 grid(B / SB), block(NTH);
  lstm2_fused<<<grid, block, 0, stream>>>(x, w_ih1, w_hh1, b_ih1, b_hh1,
                                          w_ih2, w_hh2, b_ih2, b_hh2,
                                          w_fc, b_fc, out);
}

// Round 10
// 163.326 us; speedup vs baseline: 1.2791x; 1.2791x over previous
//
#include <hip/hip_runtime.h>

// 2-layer LSTM (B=4096, T=256, I=38, H1=50, H2=15) + FC on last step.
// R10: swapped-operand MFMA — MF(W, xh) puts all 4 gate pre-acts of one
// (unit, seq) into one lane's acc[0..3] (row = 4*lk+m = 4*local_u+g,
// col = lm = seq). LSTM update is fully in-register; NO pre-act LDS.
// SB=16, 512 thr / 8 waves, grid=256 (1 block/CU), one barrier per step.
// Wave wv owns unit-tiles {wv, wv+8} (+tile16 on wv0). L2 one step behind L1.

typedef _Float16 f16x8 __attribute__((ext_vector_type(8)));
typedef float    f32x4 __attribute__((ext_vector_type(4)));

#if __has_builtin(__builtin_amdgcn_exp2f)
#define DEV_EXP2(x) __builtin_amdgcn_exp2f(x)
#else
#define DEV_EXP2(x) exp2f(x)
#endif
#if __has_builtin(__builtin_amdgcn_rcpf)
#define DEV_RCP(x) __builtin_amdgcn_rcpf(x)
#else
#define DEV_RCP(x) (1.0f/(x))
#endif

#define I1 38
#define H1 50
#define H2 15
#define NC 14
#define TT 256
#define SB 16
// A-row (f16): [x:0..37 | h1:38..87 | h2:88..102 | zero:..127 | pad..135]
#define XS 136
#define NTH 512
#define L2E 2.885390081777927f
#define L1E 1.442695040888963f

#define MF(A,B,C) __builtin_amdgcn_mfma_f32_16x16x32_f16((A),(B),(C),0,0,0)

__device__ __forceinline__ float sigm(float v)  { return DEV_RCP(1.f + DEV_EXP2(-L1E * v)); }
__device__ __forceinline__ float tanh_f(float v){ return 1.f - 2.f * DEV_RCP(1.f + DEV_EXP2(L2E * v)); }

__launch_bounds__(NTH, 1)
__global__ void lstm2_fused(const float* __restrict__ x,
                            const float* __restrict__ w_ih1, const float* __restrict__ w_hh1,
                            const float* __restrict__ b_ih1, const float* __restrict__ b_hh1,
                            const float* __restrict__ w_ih2, const float* __restrict__ w_hh2,
                            const float* __restrict__ b_ih2, const float* __restrict__ b_hh2,
                            const float* __restrict__ w_fc, const float* __restrict__ b_fc,
                            float* __restrict__ out)
{
  __shared__ __align__(16) _Float16 bufA[2][SB][XS];

  const int tid  = threadIdx.x;
  const int wv   = tid >> 6;          // 0..7
  const int lane = tid & 63;
  const int lm   = lane & 15;         // seq (B col / D col); W row for fragments
  const int lk   = lane >> 4;         // k chunk; D row group = local unit
  const int blk  = blockIdx.x;
  const float* xblk = x + (size_t)blk * SB * TT * I1;

  // ---- zero A buffers ----
  for (int i = tid; i < 2*SB*XS; i += NTH) ((_Float16*)bufA)[i] = (_Float16)0.f;

  // ---- weight element fetch (unified-k, gate-row r = 4u+g) ----
  auto welem = [&](bool il1, bool valid, int u, int g, int k) -> _Float16 {
    float w = 0.f;
    if (valid) {
      if (il1) {
        if (k < I1)                w = w_ih1[(g*H1 + u)*I1 + k];
        else if (k < I1 + H1)      w = w_hh1[(g*H1 + u)*H1 + (k - I1)];
      } else {
        if (k >= I1 && k < I1+H1)             w = w_ih2[(g*H2 + u)*H1 + (k - I1)];
        else if (k >= I1+H1 && k < I1+H1+H2)  w = w_hh2[(g*H2 + u)*H2 + (k - I1 - H1)];
      }
    }
    return (_Float16)w;
  };

  // ---- W fragments: row = lm (gate-row within tile), k = ks*32 + lk*8 + e ----
  const int t1 = wv + 8;
  const int r0 = wv*16 + lm, u0f = r0 >> 2, g0 = r0 & 3;     // tile wv: always L1
  const int r1 = t1*16 + lm, q1 = r1 >> 2, g1 = r1 & 3;
  const bool il1f = (q1 < H1);
  const int  u1f = il1f ? q1 : (q1 - H1);
  const bool w16 = (wv == 0);
  const bool c16 = w16 && (lm < 4);          // tile16 valid rows: unit 64, g=lm

  f16x8 W0[3], W1[4], W16[3];
  #pragma unroll
  for (int ks = 0; ks < 3; ++ks) {
    f16x8 v;
    #pragma unroll
    for (int e = 0; e < 8; ++e) v[e] = welem(true, true, u0f, g0, ks*32 + lk*8 + e);
    W0[ks] = v;
  }
  #pragma unroll
  for (int ks = 0; ks < 4; ++ks) {
    f16x8 v;
    #pragma unroll
    for (int e = 0; e < 8; ++e) v[e] = welem(il1f, true, u1f, g1, ks*32 + lk*8 + e);
    W1[ks] = v;
  }
  #pragma unroll
  for (int j = 0; j < 3; ++j) {
    f16x8 v;
    #pragma unroll
    for (int e = 0; e < 8; ++e) v[e] = welem(false, c16, 14, lm & 3, (j+1)*32 + lk*8 + e);
    W16[j] = v;
  }

  // ---- update geometry: lane (lm, lk) owns (unit 4*tile+lk, seq lm) ----
  const int uS0 = 4*wv + lk;                 // slot0: 0..31, always L1
  const int d0  = 38 + uS0;
  const int uS1 = 32 + 4*wv + lk;            // slot1: 32..63
  const bool il1u = (uS1 < H1);
  const int  uS1r = il1u ? uS1 : (uS1 - H1);
  const int  d1   = il1u ? (38 + uS1) : (88 + uS1r);
  const bool hasC = w16 && (lk == 0);        // tile16: unit 64 = L2 u14

  // ---- biases into MFMA C-init: acc[m] needs bias[gate m][unit] ----
  float sb0[4], sb1[4], sbC[4];
  #pragma unroll
  for (int m = 0; m < 4; ++m) {
    sb0[m] = b_ih1[m*H1 + uS0] + b_hh1[m*H1 + uS0];
    sb1[m] = il1u ? (b_ih1[m*H1 + uS1] + b_hh1[m*H1 + uS1])
                  : (b_ih2[m*H2 + uS1r] + b_hh2[m*H2 + uS1r]);
    sbC[m] = b_ih2[m*H2 + 14] + b_hh2[m*H2 + 14];
  }

  // ---- x staging: 608 f32/step over 512 threads ----
  const int e1x = tid + 512;
  const bool v1 = (tid < SB*I1 - 512);       // tid < 96
  const int s0 = tid / I1,  k0 = tid % I1;
  const int s1 = e1x / I1,  k1 = e1x % I1;
  const int gb0 = s0*TT*I1 + k0, gb1 = v1 ? (s1*TT*I1 + k1) : 0;
  const int lb0 = s0*XS + k0,    lb1 = v1 ? (s1*XS + k1) : 0;

  __syncthreads();              // zeros visible
  {                             // stage x(0)
    _Float16* b0 = &bufA[0][0][0];
    b0[lb0] = (_Float16)xblk[gb0];
    if (v1) b0[lb1] = (_Float16)xblk[gb1];
  }
  float xA0 = 0.f, xA1 = 0.f, xB0 = 0.f, xB1 = 0.f;
  xA0 = xblk[gb0 + I1];                     // prefetch x(1)
  if (v1) xA1 = xblk[gb1 + I1];
  __syncthreads();

  float cS0 = 0.f, cS1 = 0.f, cC = 0.f;

#define STEP(T, XC0, XC1, XN0, XN1) do {                                        \
    _Float16* cur = &bufA[(T) & 1][0][0];                                       \
    _Float16* nxt = &bufA[((T) & 1) ^ 1][0][0];                                 \
    if ((T) + 2 < TT) {                                                         \
      const int go = ((T) + 2) * I1;                                            \
      XN0 = xblk[gb0 + go];                                                     \
      if (v1) XN1 = xblk[gb1 + go];                                             \
    }                                                                           \
    f16x8 a0 = *(const f16x8*)(cur + lm*XS +      lk*8);                        \
    f16x8 a1 = *(const f16x8*)(cur + lm*XS + 32 + lk*8);                        \
    f16x8 a2 = *(const f16x8*)(cur + lm*XS + 64 + lk*8);                        \
    f16x8 a3 = *(const f16x8*)(cur + lm*XS + 96 + lk*8);                        \
    {                                                                           \
      f32x4 acc = (f32x4){sb0[0], sb0[1], sb0[2], sb0[3]};                      \
      acc = MF(W0[0], a0, acc);                                                 \
      acc = MF(W0[1], a1, acc);                                                 \
      acc = MF(W0[2], a2, acc);                                                 \
      if ((T) < TT) {                                                           \
        float ig = sigm(acc[0]), fg = sigm(acc[1]);                             \
        float gg = tanh_f(acc[2]), og = sigm(acc[3]);                           \
        cS0 = fg*cS0 + ig*gg;                                                   \
        nxt[lm*XS + d0] = (_Float16)(og * tanh_f(cS0));                         \
      }                                                                         \
    }                                                                           \
    {                                                                           \
      f32x4 acc = (f32x4){sb1[0], sb1[1], sb1[2], sb1[3]};                      \
      acc = MF(W1[0], a0, acc);                                                 \
      acc = MF(W1[1], a1, acc);                                                 \
      acc = MF(W1[2], a2, acc);                                                 \
      acc = MF(W1[3], a3, acc);                                                 \
      const bool up = il1u ? ((T) < TT) : ((T) >= 1);                           \
      if (up) {                                                                 \
        float ig = sigm(acc[0]), fg = sigm(acc[1]);                             \
        float gg = tanh_f(acc[2]), og = sigm(acc[3]);                           \
        cS1 = fg*cS1 + ig*gg;                                                   \
        nxt[lm*XS + d1] = (_Float16)(og * tanh_f(cS1));                         \
      }                                                                         \
    }                                                                           \
    if (w16) {                                                                  \
      f32x4 acc = (f32x4){sbC[0], sbC[1], sbC[2], sbC[3]};                      \
      acc = MF(W16[0], a1, acc);                                                \
      acc = MF(W16[1], a2, acc);                                                \
      acc = MF(W16[2], a3, acc);                                                \
      if (hasC && (T) >= 1) {                                                   \
        float ig = sigm(acc[0]), fg = sigm(acc[1]);                             \
        float gg = tanh_f(acc[2]), og = sigm(acc[3]);                           \
        cC = fg*cC + ig*gg;                                                     \
        nxt[lm*XS + 102] = (_Float16)(og * tanh_f(cC));                         \
      }                                                                         \
    }                                                                           \
    if ((T) + 1 < TT) {                                                         \
      nxt[lb0] = (_Float16)XC0;                                                 \
      if (v1) nxt[lb1] = (_Float16)XC1;                                         \
    }                                                                           \
    __syncthreads();                                                            \
  } while (0)

  int t = 0;
  for (;;) {
    STEP(t, xA0, xA1, xB0, xB1);
    if (++t > TT) break;
    STEP(t, xB0, xB1, xA0, xA1);
    if (++t > TT) break;
  }
#undef STEP

  // ---- FC on h2(255) (bufA[1], cols 88..102) ----
  if (tid < SB*NC) {
    int s = tid / NC, n = tid % NC;
    float acc = b_fc[n];
    #pragma unroll
    for (int u = 0; u < H2; ++u)
      acc += (float)bufA[1][s][88 + u] * w_fc[n*H2 + u];
    out[((size_t)blk*SB + s)*NC + n] = acc;
  }
}

extern "C" void kernel_launch(void* const* d_in, const int* in_sizes, int n_in,
                              void* d_out, int out_size, void* d_ws, size_t ws_size,
                              hipStream_t stream) {
  (void)n_in; (void)d_ws; (void)ws_size; (void)out_size;
  const float* x     = (const float*)d_in[0];
  const float* w_ih1 = (const float*)d_in[1];
  const float* w_hh1 = (const float*)d_in[2];
  const float* b_ih1 = (const float*)d_in[3];
  const float* b_hh1 = (const float*)d_in[4];
  const float* w_ih2 = (const float*)d_in[5];
  const float* w_hh2 = (const float*)d_in[6];
  const float* b_ih2 = (const float*)d_in[7];
  const float* b_hh2 = (const float*)d_in[8];
  const float* w_fc  = (const float*)d_in[9];
  const float* b_fc  = (const float*)d_in[10];
  float* out = (float*)d_out;

  const int B = in_sizes[0] / (TT * I1);   // 4096
  dim3 grid(B / SB), block(NTH);
  lstm2_fused<<<grid, block, 0, stream>>>(x, w_ih1, w_hh1, b_ih1, b_hh1,
                                          w_ih2, w_hh2, b_ih2, b_hh2,
                                          w_fc, b_fc, out);
}